// Round 2
// baseline (272.929 us; speedup 1.0000x reference)
//
#include <hip/hip_runtime.h>
#include <hip/hip_bf16.h>
#include <cstdint>
#include <cstddef>

typedef __bf16 bf16_t;
typedef __bf16 bf16x8 __attribute__((ext_vector_type(8)));
typedef __bf16 bf16x4 __attribute__((ext_vector_type(4)));
typedef float  f32x4  __attribute__((ext_vector_type(4)));

#define KDIM 1024
#define NT   16        // K-tiles per 256x256 output tile
#define NTT  32        // 2 reps * NT: continuous K-tile count per block

// ---------------------------------------------------------------------------
// Kernel 1 (fused prep): blocks [0,Bn): softmax(mod)+1 scale of x -> bf16 A.
//                        blocks [Bn, Bn + C*D/2048): fp32->bf16 cast of W.
// ---------------------------------------------------------------------------
__global__ void prep_kernel(const float* __restrict__ x,
                            const float* __restrict__ mod,
                            const float* __restrict__ W,
                            bf16_t* __restrict__ a,
                            bf16_t* __restrict__ Wb,
                            int D, int Bn) {
  if ((int)blockIdx.x >= Bn) {
    const size_t i = (((size_t)blockIdx.x - Bn) * blockDim.x + threadIdx.x) * 8;
    float4 u = *(const float4*)(W + i);
    float4 v = *(const float4*)(W + i + 4);
    bf16x8 o;
    o[0] = (bf16_t)u.x; o[1] = (bf16_t)u.y; o[2] = (bf16_t)u.z; o[3] = (bf16_t)u.w;
    o[4] = (bf16_t)v.x; o[5] = (bf16_t)v.y; o[6] = (bf16_t)v.z; o[7] = (bf16_t)v.w;
    *(bf16x8*)(Wb + i) = o;
    return;
  }

  const int b = blockIdx.x;
  const int t = threadIdx.x;
  const size_t row = (size_t)b * D;

  float4 mv = ((const float4*)(mod + row))[t];
  float mx = fmaxf(fmaxf(mv.x, mv.y), fmaxf(mv.z, mv.w));
#pragma unroll
  for (int o = 32; o > 0; o >>= 1) mx = fmaxf(mx, __shfl_xor(mx, o));

  __shared__ float redmax[4];
  __shared__ float redsum[4];
  const int wave = t >> 6, lane = t & 63;
  if (lane == 0) redmax[wave] = mx;
  __syncthreads();
  mx = fmaxf(fmaxf(redmax[0], redmax[1]), fmaxf(redmax[2], redmax[3]));

  float4 e;
  e.x = __expf(mv.x - mx); e.y = __expf(mv.y - mx);
  e.z = __expf(mv.z - mx); e.w = __expf(mv.w - mx);
  float s = (e.x + e.y) + (e.z + e.w);
#pragma unroll
  for (int o = 32; o > 0; o >>= 1) s += __shfl_xor(s, o);
  if (lane == 0) redsum[wave] = s;
  __syncthreads();
  s = (redsum[0] + redsum[1]) + (redsum[2] + redsum[3]);

  const float inv = 1.0f / s;
  float4 xv = ((const float4*)(x + row))[t];
  bf16x4 o4;
  o4[0] = (bf16_t)((e.x * inv + 1.0f) * xv.x);
  o4[1] = (bf16_t)((e.y * inv + 1.0f) * xv.y);
  o4[2] = (bf16_t)((e.z * inv + 1.0f) * xv.z);
  o4[3] = (bf16_t)((e.w * inv + 1.0f) * xv.w);
  *((bf16x4*)(a + row) + t) = o4;
}

// ---------------------------------------------------------------------------
// Kernel 2: paired-tile 8-phase bf16 GEMM (B^T input), counted vmcnt.
//   C[m][n] = sum_k A[m][k] * B[n][k];  A:(M,K) bf16, B:(N,K) bf16, C fp32.
// Each block: TWO 256x256 output tiles (m-pair, shared B panel) computed as
// one continuous 32-K-tile pipeline; rep-0 C-flush at t==15 retires under
// rep-1 compute. 8 waves (2M x 4N); BK=64; LDS = 2buf x (A 32K + B 32K).
// XOR swizzle (c8 ^= row&7) on global source at stage time (LDS dest linear
// for global_load_lds) and on the column index at ds_read time.
// Per K-tile t: 4 phases (A-row-quadrants), each {4 ds_read ∥ 1 half-tile
// global_load_lds issue -> barrier -> lgkmcnt(0) -> setprio(1) 16 MFMA ->
// barrier}; vmcnt(4) once per tile (phase 3), never 0 in steady state.
// ---------------------------------------------------------------------------
__global__ __launch_bounds__(512, 2) void gemm256_kernel(
    const bf16_t* __restrict__ A, const bf16_t* __restrict__ B,
    float* __restrict__ C, int M, int N) {
  __shared__ __align__(16) bf16_t lds[2 * 32768];   // 128 KiB

  const int tid  = threadIdx.x;
  const int wave = tid >> 6;
  const int lane = tid & 63;
  const int quad = lane >> 4;
  const int l16  = lane & 15;
  const int wm   = wave >> 2;      // 0..1 -> 128 M-rows
  const int wn   = wave & 3;       // 0..3 -> 64 N-cols

  // XCD-aware bijective swizzle (nwg = 256, % 8 == 0), n-major decomposition:
  // per-XCD chunk = 2 m-pairs x 16 n-tiles -> A (2MB) and B panels L2-hot.
  const int nwg = gridDim.x;
  int flat = blockIdx.x;
  flat = (flat & 7) * (nwg >> 3) + (flat >> 3);
  const int mpairs = M >> 9;                 // 16
  const int m0 = (flat % mpairs) << 9;       // 512 rows per block (2 reps)
  const int n0 = (flat / mpairs) << 8;       // 256 cols

  // Staging: slot s = i*512 + tid within a half-tile (128 rows x 8 c8-groups).
  const int trow = tid >> 3;                       // 0..63
  const int colg = (tid & 7) ^ (trow & 7);
  const bf16_t* aSrc = A + (size_t)(m0 + trow) * KDIM + colg * 8;
  const bf16_t* bSrc = B + (size_t)(n0 + trow) * KDIM + colg * 8;
  const int ldsW = wave * 512;                     // wave-uniform dest offset

#define GLDS(src_, dst_) __builtin_amdgcn_global_load_lds( \
      (const __attribute__((address_space(1))) void*)(src_), \
      (__attribute__((address_space(3))) void*)(dst_), 16, 0, 0)

  // Global K-tile index t_ in [0, 32): rep = t_>>4, K-offset = (t_&15)*64.
#define ISSUE_A(h, t_) do { \
      const bf16_t* s_ = aSrc + (size_t)((((t_) >> 4) * 256) + (h) * 128) * KDIM + ((t_) & 15) * 64; \
      bf16_t* d_ = lds + ((t_) & 1) * 32768 + (h) * 8192 + ldsW; \
      GLDS(s_, d_); \
      GLDS(s_ + (size_t)64 * KDIM, d_ + 4096); \
    } while (0)

#define ISSUE_B(h, t_) do { \
      const bf16_t* s_ = bSrc + (size_t)((h) * 128) * KDIM + ((t_) & 15) * 64; \
      bf16_t* d_ = lds + ((t_) & 1) * 32768 + 16384 + (h) * 8192 + ldsW; \
      GLDS(s_, d_); \
      GLDS(s_ + (size_t)64 * KDIM, d_ + 4096); \
    } while (0)

  // Prologue: tile0 A+B (4 half-tiles), tile1 B (2 half-tiles).
  ISSUE_A(0, 0); ISSUE_A(1, 0);
  ISSUE_B(0, 0); ISSUE_B(1, 0);
  ISSUE_B(0, 1); ISSUE_B(1, 1);

  f32x4 acc[8][4];
#pragma unroll
  for (int i = 0; i < 8; ++i)
#pragma unroll
    for (int j = 0; j < 4; ++j) acc[i][j] = (f32x4){0.f, 0.f, 0.f, 0.f};

  const int aBase = (wm * 128 + l16) * 64;
  const int bBase = (wn * 64 + l16) * 64;
  const int c0 = ((quad)     ^ (l16 & 7)) * 8;
  const int c1 = ((4 + quad) ^ (l16 & 7)) * 8;

  // Wait for tile0 (first 8 loads); tile1's B (last 4) stays in flight.
  asm volatile("s_waitcnt vmcnt(4)" ::: "memory");
  __builtin_amdgcn_s_barrier();

  bf16x8 bfr[4][2];

#define PHASE(q_, ISSUE_STMT, WAIT_STMT) do { \
      bf16x8 af[2][2]; \
      _Pragma("unroll") \
      for (int i = 0; i < 2; ++i) { \
        af[i][0] = *(const bf16x8*)(At + aBase + ((q_) * 32 + i * 16) * 64 + c0); \
        af[i][1] = *(const bf16x8*)(At + aBase + ((q_) * 32 + i * 16) * 64 + c1); \
      } \
      ISSUE_STMT; \
      asm volatile("" ::: "memory"); \
      __builtin_amdgcn_s_barrier(); \
      asm volatile("s_waitcnt lgkmcnt(0)" ::: "memory"); \
      __builtin_amdgcn_s_setprio(1); \
      _Pragma("unroll") \
      for (int i = 0; i < 2; ++i) \
        _Pragma("unroll") \
        for (int j = 0; j < 4; ++j) { \
          acc[(q_) * 2 + i][j] = __builtin_amdgcn_mfma_f32_16x16x32_bf16( \
              af[i][0], bfr[j][0], acc[(q_) * 2 + i][j], 0, 0, 0); \
          acc[(q_) * 2 + i][j] = __builtin_amdgcn_mfma_f32_16x16x32_bf16( \
              af[i][1], bfr[j][1], acc[(q_) * 2 + i][j], 0, 0, 0); \
        } \
      __builtin_amdgcn_s_setprio(0); \
      WAIT_STMT; \
      asm volatile("" ::: "memory"); \
      __builtin_amdgcn_s_barrier(); \
    } while (0)

#define FLUSH(mrep_) do { \
      _Pragma("unroll") \
      for (int ri = 0; ri < 8; ++ri) { \
        const int mg = m0 + (mrep_) * 256 + wm * 128 + ri * 16 + quad * 4; \
        _Pragma("unroll") \
        for (int j = 0; j < 4; ++j) { \
          const int ng = n0 + wn * 64 + j * 16 + l16; \
          _Pragma("unroll") \
          for (int r = 0; r < 4; ++r) \
            C[(size_t)(mg + r) * N + ng] = acc[ri][j][r]; \
        } \
      } \
    } while (0)

#pragma unroll 1
  for (int t = 0; t < NTT; ++t) {
    const bf16_t* At = lds + (t & 1) * 32768;
    const bf16_t* Bt = At + 16384;

    // Full B panel for this K-tile (8 ds_read_b128), pre-phase-0.
#pragma unroll
    for (int j = 0; j < 4; ++j) {
      bfr[j][0] = *(const bf16x8*)(Bt + bBase + j * 16 * 64 + c0);
      bfr[j][1] = *(const bf16x8*)(Bt + bBase + j * 16 * 64 + c1);
    }
    PHASE(0, if (t + 1 < NTT) ISSUE_A(0, t + 1), (void)0);
    PHASE(1, if (t + 1 < NTT) ISSUE_A(1, t + 1), (void)0);
    PHASE(2, if (t + 2 < NTT) ISSUE_B(0, t + 2), (void)0);
    PHASE(3, if (t + 2 < NTT) ISSUE_B(1, t + 2),
          if (t < NTT - 2) { asm volatile("s_waitcnt vmcnt(4)" ::: "memory"); }
          else             { asm volatile("s_waitcnt vmcnt(0)" ::: "memory"); });

    if (t == NT - 1) {
      // Rep-0 C-flush: stores retire to L2 under rep-1 compute. No LDS touch,
      // no barrier needed (next phase's start barrier re-syncs).
      FLUSH(0);
#pragma unroll
      for (int i = 0; i < 8; ++i)
#pragma unroll
        for (int j = 0; j < 4; ++j) acc[i][j] = (f32x4){0.f, 0.f, 0.f, 0.f};
    }
  }

  FLUSH(1);
}

// ---------------------------------------------------------------------------
extern "C" void kernel_launch(void* const* d_in, const int* in_sizes, int n_in,
                              void* d_out, int out_size, void* d_ws, size_t ws_size,
                              hipStream_t stream) {
  const float* x   = (const float*)d_in[0];
  const float* mod = (const float*)d_in[1];
  const float* W   = (const float*)d_in[2];
  float* out = (float*)d_out;

  const int D = 1024;
  const int Bn = in_sizes[0] / D;  // 8192
  const int Cn = in_sizes[2] / D;  // 4096

  bf16_t* a  = (bf16_t*)d_ws;                                             // B*D bf16
  bf16_t* Wb = (bf16_t*)((char*)d_ws + (size_t)Bn * D * sizeof(bf16_t));  // C*D bf16

  const int castBlocks = (Cn * D) / (256 * 8);   // 2048
  prep_kernel<<<Bn + castBlocks, 256, 0, stream>>>(x, mod, W, a, Wb, D, Bn);

  const int nwg = (Bn / 512) * (Cn / 256);  // 16*16 = 256, % 8 == 0
  gemm256_kernel<<<nwg, 512, 0, stream>>>(a, Wb, out, Bn, Cn);
}

// Round 3
// 256.719 us; speedup vs baseline: 1.0631x; 1.0631x over previous
//
#include <hip/hip_runtime.h>
#include <hip/hip_bf16.h>
#include <cstdint>
#include <cstddef>

typedef __bf16 bf16_t;
typedef __bf16 bf16x8 __attribute__((ext_vector_type(8)));
typedef __bf16 bf16x4 __attribute__((ext_vector_type(4)));
typedef float  f32x4  __attribute__((ext_vector_type(4)));

#define KDIM 1024
#define NT   16        // K-tiles per 256x256 output tile
#define NTT  32        // 2 reps * NT: continuous K-tile count per block

// ---------------------------------------------------------------------------
// Kernel 1 (fused prep): blocks [0,Bn): softmax(mod)+1 scale of x -> bf16 A.
//                        blocks [Bn, ...): fp32->bf16 cast of W.
// ---------------------------------------------------------------------------
__global__ void prep_kernel(const float* __restrict__ x,
                            const float* __restrict__ mod,
                            const float* __restrict__ W,
                            bf16_t* __restrict__ a,
                            bf16_t* __restrict__ Wb,
                            int D, int Bn) {
  if ((int)blockIdx.x >= Bn) {
    const size_t i = (((size_t)blockIdx.x - Bn) * blockDim.x + threadIdx.x) * 8;
    float4 u = *(const float4*)(W + i);
    float4 v = *(const float4*)(W + i + 4);
    bf16x8 o;
    o[0] = (bf16_t)u.x; o[1] = (bf16_t)u.y; o[2] = (bf16_t)u.z; o[3] = (bf16_t)u.w;
    o[4] = (bf16_t)v.x; o[5] = (bf16_t)v.y; o[6] = (bf16_t)v.z; o[7] = (bf16_t)v.w;
    *(bf16x8*)(Wb + i) = o;
    return;
  }

  const int b = blockIdx.x;
  const int t = threadIdx.x;
  const size_t row = (size_t)b * D;

  float4 mv = ((const float4*)(mod + row))[t];
  float mx = fmaxf(fmaxf(mv.x, mv.y), fmaxf(mv.z, mv.w));
#pragma unroll
  for (int o = 32; o > 0; o >>= 1) mx = fmaxf(mx, __shfl_xor(mx, o));

  __shared__ float redmax[4];
  __shared__ float redsum[4];
  const int wave = t >> 6, lane = t & 63;
  if (lane == 0) redmax[wave] = mx;
  __syncthreads();
  mx = fmaxf(fmaxf(redmax[0], redmax[1]), fmaxf(redmax[2], redmax[3]));

  float4 e;
  e.x = __expf(mv.x - mx); e.y = __expf(mv.y - mx);
  e.z = __expf(mv.z - mx); e.w = __expf(mv.w - mx);
  float s = (e.x + e.y) + (e.z + e.w);
#pragma unroll
  for (int o = 32; o > 0; o >>= 1) s += __shfl_xor(s, o);
  if (lane == 0) redsum[wave] = s;
  __syncthreads();
  s = (redsum[0] + redsum[1]) + (redsum[2] + redsum[3]);

  const float inv = 1.0f / s;
  float4 xv = ((const float4*)(x + row))[t];
  bf16x4 o4;
  o4[0] = (bf16_t)((e.x * inv + 1.0f) * xv.x);
  o4[1] = (bf16_t)((e.y * inv + 1.0f) * xv.y);
  o4[2] = (bf16_t)((e.z * inv + 1.0f) * xv.z);
  o4[3] = (bf16_t)((e.w * inv + 1.0f) * xv.w);
  *((bf16x4*)(a + row) + t) = o4;
}

// ---------------------------------------------------------------------------
// Kernel 2: paired-tile 8-phase bf16 GEMM (B^T input), counted vmcnt.
// Each block: TWO 256x256 output tiles (m-pair, shared B panel) as one
// continuous 32-K-tile pipeline. Rep-0's C-flush is STAGGERED across the
// phase slots where each acc row-pair is dead (finalized by t15-phase q,
// reused at t16-phase q), so stores never head-of-line-block a counted wait:
//   rows01: after t15-ph2 MFMA      rows23: after t15-ph3 WAIT
//   rows45: after t16-ph0 MFMA      rows67: after t16-ph1 MFMA
// vmcnt queue arithmetic (in-order retirement):
//   t15-ph3 needs A(16)h1; ops after it = [B17h0:2][st32][B17h1:2] -> vmcnt(36)
//   t16-ph3 needs A(17)h1; ops after it = [st32][B18:4]            -> vmcnt(36)
//   all other tiles: vmcnt(4). Store blocks are >=1 tile old at any vmcnt(4).
// ---------------------------------------------------------------------------
__global__ __launch_bounds__(512, 2) void gemm256_kernel(
    const bf16_t* __restrict__ A, const bf16_t* __restrict__ B,
    float* __restrict__ C, int M, int N) {
  __shared__ __align__(16) bf16_t lds[2 * 32768];   // 128 KiB

  const int tid  = threadIdx.x;
  const int wave = tid >> 6;
  const int lane = tid & 63;
  const int quad = lane >> 4;
  const int l16  = lane & 15;
  const int wm   = wave >> 2;      // 0..1 -> 128 M-rows
  const int wn   = wave & 3;       // 0..3 -> 64 N-cols

  // XCD-aware bijective swizzle (nwg = 256, % 8 == 0), n-major chunks.
  const int nwg = gridDim.x;
  int flat = blockIdx.x;
  flat = (flat & 7) * (nwg >> 3) + (flat >> 3);
  const int mpairs = M >> 9;                 // 16
  const int m0 = (flat % mpairs) << 9;       // 512 rows per block (2 reps)
  const int n0 = (flat / mpairs) << 8;       // 256 cols

  const int trow = tid >> 3;                       // 0..63
  const int colg = (tid & 7) ^ (trow & 7);
  const bf16_t* aSrc = A + (size_t)(m0 + trow) * KDIM + colg * 8;
  const bf16_t* bSrc = B + (size_t)(n0 + trow) * KDIM + colg * 8;
  const int ldsW = wave * 512;                     // wave-uniform dest offset

#define GLDS(src_, dst_) __builtin_amdgcn_global_load_lds( \
      (const __attribute__((address_space(1))) void*)(src_), \
      (__attribute__((address_space(3))) void*)(dst_), 16, 0, 0)

  // Global K-tile index t_ in [0,32): rep = t_>>4, K-offset = (t_&15)*64.
#define ISSUE_A(h, t_) do { \
      const bf16_t* s_ = aSrc + (size_t)((((t_) >> 4) * 256) + (h) * 128) * KDIM + ((t_) & 15) * 64; \
      bf16_t* d_ = lds + ((t_) & 1) * 32768 + (h) * 8192 + ldsW; \
      GLDS(s_, d_); \
      GLDS(s_ + (size_t)64 * KDIM, d_ + 4096); \
    } while (0)

#define ISSUE_B(h, t_) do { \
      const bf16_t* s_ = bSrc + (size_t)((h) * 128) * KDIM + ((t_) & 15) * 64; \
      bf16_t* d_ = lds + ((t_) & 1) * 32768 + 16384 + (h) * 8192 + ldsW; \
      GLDS(s_, d_); \
      GLDS(s_ + (size_t)64 * KDIM, d_ + 4096); \
    } while (0)

  // Prologue: tile0 A+B (4 half-tiles), tile1 B (2 half-tiles).
  ISSUE_A(0, 0); ISSUE_A(1, 0);
  ISSUE_B(0, 0); ISSUE_B(1, 0);
  ISSUE_B(0, 1); ISSUE_B(1, 1);

  f32x4 acc[8][4];
#pragma unroll
  for (int i = 0; i < 8; ++i)
#pragma unroll
    for (int j = 0; j < 4; ++j) acc[i][j] = (f32x4){0.f, 0.f, 0.f, 0.f};

  const int aBase = (wm * 128 + l16) * 64;
  const int bBase = (wn * 64 + l16) * 64;
  const int c0 = ((quad)     ^ (l16 & 7)) * 8;
  const int c1 = ((4 + quad) ^ (l16 & 7)) * 8;

  asm volatile("s_waitcnt vmcnt(4)" ::: "memory");
  __builtin_amdgcn_s_barrier();

  bf16x8 bfr[4][2];

#define BPANEL(Bt_) do { \
      _Pragma("unroll") \
      for (int j = 0; j < 4; ++j) { \
        bfr[j][0] = *(const bf16x8*)((Bt_) + bBase + j * 16 * 64 + c0); \
        bfr[j][1] = *(const bf16x8*)((Bt_) + bBase + j * 16 * 64 + c1); \
      } \
    } while (0)

  // Flush rep-0 rows r0_, r0_+1 (32 scalar dword stores), then zero them.
#define FLUSH_PAIR(r0_) do { \
      _Pragma("unroll") \
      for (int ri = (r0_); ri < (r0_) + 2; ++ri) { \
        const int mg = m0 + wm * 128 + ri * 16 + quad * 4; \
        _Pragma("unroll") \
        for (int j = 0; j < 4; ++j) { \
          const int ng = n0 + wn * 64 + j * 16 + l16; \
          _Pragma("unroll") \
          for (int r = 0; r < 4; ++r) \
            C[(size_t)(mg + r) * N + ng] = acc[ri][j][r]; \
        } \
        _Pragma("unroll") \
        for (int j = 0; j < 4; ++j) acc[ri][j] = (f32x4){0.f, 0.f, 0.f, 0.f}; \
      } \
    } while (0)

#define PHASE(q_, ISSUE_STMT, PREWAIT_STMT, WAIT_STMT, POSTWAIT_STMT) do { \
      bf16x8 af[2][2]; \
      _Pragma("unroll") \
      for (int i = 0; i < 2; ++i) { \
        af[i][0] = *(const bf16x8*)(At + aBase + ((q_) * 32 + i * 16) * 64 + c0); \
        af[i][1] = *(const bf16x8*)(At + aBase + ((q_) * 32 + i * 16) * 64 + c1); \
      } \
      ISSUE_STMT; \
      asm volatile("" ::: "memory"); \
      __builtin_amdgcn_s_barrier(); \
      asm volatile("s_waitcnt lgkmcnt(0)" ::: "memory"); \
      __builtin_amdgcn_s_setprio(1); \
      _Pragma("unroll") \
      for (int i = 0; i < 2; ++i) \
        _Pragma("unroll") \
        for (int j = 0; j < 4; ++j) { \
          acc[(q_) * 2 + i][j] = __builtin_amdgcn_mfma_f32_16x16x32_bf16( \
              af[i][0], bfr[j][0], acc[(q_) * 2 + i][j], 0, 0, 0); \
          acc[(q_) * 2 + i][j] = __builtin_amdgcn_mfma_f32_16x16x32_bf16( \
              af[i][1], bfr[j][1], acc[(q_) * 2 + i][j], 0, 0, 0); \
        } \
      __builtin_amdgcn_s_setprio(0); \
      PREWAIT_STMT; \
      WAIT_STMT; \
      POSTWAIT_STMT; \
      asm volatile("" ::: "memory"); \
      __builtin_amdgcn_s_barrier(); \
    } while (0)

#define TILE_STD(t_) do { \
      const bf16_t* At = lds + ((t_) & 1) * 32768; \
      const bf16_t* Bt = At + 16384; \
      BPANEL(Bt); \
      PHASE(0, if ((t_) + 1 < NTT) ISSUE_A(0, (t_) + 1), (void)0, (void)0, (void)0); \
      PHASE(1, if ((t_) + 1 < NTT) ISSUE_A(1, (t_) + 1), (void)0, (void)0, (void)0); \
      PHASE(2, if ((t_) + 2 < NTT) ISSUE_B(0, (t_) + 2), (void)0, (void)0, (void)0); \
      PHASE(3, if ((t_) + 2 < NTT) ISSUE_B(1, (t_) + 2), (void)0, \
            if ((t_) < NTT - 2) { asm volatile("s_waitcnt vmcnt(4)" ::: "memory"); } \
            else                { asm volatile("s_waitcnt vmcnt(0)" ::: "memory"); }, \
            (void)0); \
    } while (0)

#pragma unroll 1
  for (int t = 0; t < 15; ++t) TILE_STD(t);

  // ---- tile 15 (peeled): rep-0 K complete per-quadrant; staggered flush ----
  {
    const bf16_t* At = lds + 32768;   // (15 & 1) * 32768
    const bf16_t* Bt = At + 16384;
    BPANEL(Bt);
    PHASE(0, ISSUE_A(0, 16), (void)0, (void)0, (void)0);
    PHASE(1, ISSUE_A(1, 16), (void)0, (void)0, (void)0);
    PHASE(2, ISSUE_B(0, 17), FLUSH_PAIR(0), (void)0, (void)0);
    PHASE(3, ISSUE_B(1, 17), (void)0,
          asm volatile("s_waitcnt vmcnt(36)" ::: "memory"),
          FLUSH_PAIR(2));
  }
  // ---- tile 16 (peeled): finish staggered flush ----
  {
    const bf16_t* At = lds;           // (16 & 1) * 32768
    const bf16_t* Bt = At + 16384;
    BPANEL(Bt);
    PHASE(0, ISSUE_A(0, 17), FLUSH_PAIR(4), (void)0, (void)0);
    PHASE(1, ISSUE_A(1, 17), FLUSH_PAIR(6), (void)0, (void)0);
    PHASE(2, ISSUE_B(0, 18), (void)0, (void)0, (void)0);
    PHASE(3, ISSUE_B(1, 18), (void)0,
          asm volatile("s_waitcnt vmcnt(36)" ::: "memory"), (void)0);
  }

#pragma unroll 1
  for (int t = 17; t < NTT; ++t) TILE_STD(t);

  // Final epilogue: rep-1 flush.
#pragma unroll
  for (int ri = 0; ri < 8; ++ri) {
    const int mg = m0 + 256 + wm * 128 + ri * 16 + quad * 4;
#pragma unroll
    for (int j = 0; j < 4; ++j) {
      const int ng = n0 + wn * 64 + j * 16 + l16;
#pragma unroll
      for (int r = 0; r < 4; ++r)
        C[(size_t)(mg + r) * N + ng] = acc[ri][j][r];
    }
  }
}

// ---------------------------------------------------------------------------
extern "C" void kernel_launch(void* const* d_in, const int* in_sizes, int n_in,
                              void* d_out, int out_size, void* d_ws, size_t ws_size,
                              hipStream_t stream) {
  const float* x   = (const float*)d_in[0];
  const float* mod = (const float*)d_in[1];
  const float* W   = (const float*)d_in[2];
  float* out = (float*)d_out;

  const int D = 1024;
  const int Bn = in_sizes[0] / D;  // 8192
  const int Cn = in_sizes[2] / D;  // 4096

  bf16_t* a  = (bf16_t*)d_ws;                                             // B*D bf16
  bf16_t* Wb = (bf16_t*)((char*)d_ws + (size_t)Bn * D * sizeof(bf16_t));  // C*D bf16

  const int castBlocks = (Cn * D) / (256 * 8);   // 2048
  prep_kernel<<<Bn + castBlocks, 256, 0, stream>>>(x, mod, W, a, Wb, D, Bn);

  const int nwg = (Bn / 512) * (Cn / 256);  // 16*16 = 256, % 8 == 0
  gemm256_kernel<<<nwg, 512, 0, stream>>>(a, Wb, out, Bn, Cn);
}

// Round 4
// 256.238 us; speedup vs baseline: 1.0651x; 1.0019x over previous
//
#include <hip/hip_runtime.h>
#include <hip/hip_bf16.h>
#include <cstdint>
#include <cstddef>

typedef __bf16 bf16_t;
typedef __bf16 bf16x8 __attribute__((ext_vector_type(8)));
typedef __bf16 bf16x4 __attribute__((ext_vector_type(4)));
typedef float  f32x4  __attribute__((ext_vector_type(4)));

#define KDIM 1024
#define NT   16        // K-tiles per 256x256 output tile

// ---------------------------------------------------------------------------
// Kernel 1 (fused prep): blocks [0,Bn): softmax(mod)+1 scale of x -> bf16 A.
//                        blocks [Bn, ...): fp32->bf16 cast of W.
// ---------------------------------------------------------------------------
__global__ void prep_kernel(const float* __restrict__ x,
                            const float* __restrict__ mod,
                            const float* __restrict__ W,
                            bf16_t* __restrict__ a,
                            bf16_t* __restrict__ Wb,
                            int D, int Bn) {
  if ((int)blockIdx.x >= Bn) {
    const size_t i = (((size_t)blockIdx.x - Bn) * blockDim.x + threadIdx.x) * 8;
    float4 u = *(const float4*)(W + i);
    float4 v = *(const float4*)(W + i + 4);
    bf16x8 o;
    o[0] = (bf16_t)u.x; o[1] = (bf16_t)u.y; o[2] = (bf16_t)u.z; o[3] = (bf16_t)u.w;
    o[4] = (bf16_t)v.x; o[5] = (bf16_t)v.y; o[6] = (bf16_t)v.z; o[7] = (bf16_t)v.w;
    *(bf16x8*)(Wb + i) = o;
    return;
  }

  const int b = blockIdx.x;
  const int t = threadIdx.x;
  const size_t row = (size_t)b * D;

  float4 mv = ((const float4*)(mod + row))[t];
  float mx = fmaxf(fmaxf(mv.x, mv.y), fmaxf(mv.z, mv.w));
#pragma unroll
  for (int o = 32; o > 0; o >>= 1) mx = fmaxf(mx, __shfl_xor(mx, o));

  __shared__ float redmax[4];
  __shared__ float redsum[4];
  const int wave = t >> 6, lane = t & 63;
  if (lane == 0) redmax[wave] = mx;
  __syncthreads();
  mx = fmaxf(fmaxf(redmax[0], redmax[1]), fmaxf(redmax[2], redmax[3]));

  float4 e;
  e.x = __expf(mv.x - mx); e.y = __expf(mv.y - mx);
  e.z = __expf(mv.z - mx); e.w = __expf(mv.w - mx);
  float s = (e.x + e.y) + (e.z + e.w);
#pragma unroll
  for (int o = 32; o > 0; o >>= 1) s += __shfl_xor(s, o);
  if (lane == 0) redsum[wave] = s;
  __syncthreads();
  s = (redsum[0] + redsum[1]) + (redsum[2] + redsum[3]);

  const float inv = 1.0f / s;
  float4 xv = ((const float4*)(x + row))[t];
  bf16x4 o4;
  o4[0] = (bf16_t)((e.x * inv + 1.0f) * xv.x);
  o4[1] = (bf16_t)((e.y * inv + 1.0f) * xv.y);
  o4[2] = (bf16_t)((e.z * inv + 1.0f) * xv.z);
  o4[3] = (bf16_t)((e.w * inv + 1.0f) * xv.w);
  *((bf16x4*)(a + row) + t) = o4;
}

// ---------------------------------------------------------------------------
// Kernel 2: 256x256-tile 8-phase bf16 GEMM (B^T input), counted vmcnt AND
// counted lgkmcnt with one-phase ds_read look-ahead.
//   C[m][n] = sum_k A[m][k] * B[n][k];  A:(M,K) bf16, B:(N,K) bf16, C fp32.
// 8 waves (2M x 4N); per-wave output 128x64; BK=64; LDS 2buf x (A32K+B32K).
// XOR swizzle (c8 ^= row&7) on global source at stage time + on ds_read col.
// Per tile t (buffer X = t&1):
//   prime: B-panel reads (8) + A-quadrant-0 reads (4)        [12 lgkm]
//   ph0: read q1->afB | GLDS A0(t+1) | bar | lgkmcnt(4) | MFMA q0(afA) | bar
//   ph1: read q2->afA | GLDS A1(t+1) | bar | lgkmcnt(4) | MFMA q1(afB) | bar
//   ph2: read q3->afB | GLDS B0(t+2) | bar | lgkmcnt(4) | MFMA q2(afA) | bar
//   ph3:              | GLDS B1(t+2) | bar | lgkmcnt(0) | MFMA q3(afB)
//        | vmcnt(4) | bar
// Look-ahead reads hide under the previous phase's MFMA -> LDS pipe and MFMA
// pipe overlap instead of convoying. sched_barrier(0) after each counted
// lgkmcnt stops the compiler hoisting MFMA above the wait (rule #18).
// B(t+2) overwrites buffer X's B region only after ph0's wait drained the
// B-panel into registers -> legal. vmcnt(4) at tile end, never 0 mid-loop.
// ---------------------------------------------------------------------------
__global__ __launch_bounds__(512, 2) void gemm256_kernel(
    const bf16_t* __restrict__ A, const bf16_t* __restrict__ B,
    float* __restrict__ C, int M, int N) {
  __shared__ __align__(16) bf16_t lds[2 * 32768];   // 128 KiB

  const int tid  = threadIdx.x;
  const int wave = tid >> 6;
  const int lane = tid & 63;
  const int quad = lane >> 4;
  const int l16  = lane & 15;
  const int wm   = wave >> 2;      // 0..1 -> 128 M-rows
  const int wn   = wave & 3;       // 0..3 -> 64 N-cols

  // XCD-aware bijective swizzle (nwg = 512, % 8 == 0).
  const int nwg = gridDim.x;
  int flat = blockIdx.x;
  flat = (flat & 7) * (nwg >> 3) + (flat >> 3);
  const int ntiles = N >> 8;
  const int m0 = (flat / ntiles) << 8;
  const int n0 = (flat % ntiles) << 8;

  // Staging: slot s = i*512 + tid within a half-tile (128 rows x 8 c8-groups).
  const int trow = tid >> 3;                       // 0..63
  const int colg = (tid & 7) ^ (trow & 7);
  const bf16_t* aSrc = A + (size_t)(m0 + trow) * KDIM + colg * 8;
  const bf16_t* bSrc = B + (size_t)(n0 + trow) * KDIM + colg * 8;
  const int ldsW = wave * 512;                     // wave-uniform dest offset

#define GLDS(src_, dst_) __builtin_amdgcn_global_load_lds( \
      (const __attribute__((address_space(1))) void*)(src_), \
      (__attribute__((address_space(3))) void*)(dst_), 16, 0, 0)

#define ISSUE_A(h, t_) do { \
      const bf16_t* s_ = aSrc + (size_t)((h) * 128) * KDIM + (t_) * 64; \
      bf16_t* d_ = lds + ((t_) & 1) * 32768 + (h) * 8192 + ldsW; \
      GLDS(s_, d_); \
      GLDS(s_ + (size_t)64 * KDIM, d_ + 4096); \
    } while (0)

#define ISSUE_B(h, t_) do { \
      const bf16_t* s_ = bSrc + (size_t)((h) * 128) * KDIM + (t_) * 64; \
      bf16_t* d_ = lds + ((t_) & 1) * 32768 + 16384 + (h) * 8192 + ldsW; \
      GLDS(s_, d_); \
      GLDS(s_ + (size_t)64 * KDIM, d_ + 4096); \
    } while (0)

  // Prologue: tile0 A+B (8 loads), tile1 B (4 loads).
  ISSUE_A(0, 0); ISSUE_A(1, 0);
  ISSUE_B(0, 0); ISSUE_B(1, 0);
  ISSUE_B(0, 1); ISSUE_B(1, 1);

  f32x4 acc[8][4];
#pragma unroll
  for (int i = 0; i < 8; ++i)
#pragma unroll
    for (int j = 0; j < 4; ++j) acc[i][j] = (f32x4){0.f, 0.f, 0.f, 0.f};

  const int aBase = (wm * 128 + l16) * 64;
  const int bBase = (wn * 64 + l16) * 64;
  const int c0 = ((quad)     ^ (l16 & 7)) * 8;     // kt=0 swizzled column
  const int c1 = ((4 + quad) ^ (l16 & 7)) * 8;     // kt=1

  // Wait for tile0 (first 8 loads); tile1's B (last 4) stays in flight.
  asm volatile("s_waitcnt vmcnt(4)" ::: "memory");
  __builtin_amdgcn_s_barrier();

  bf16x8 bfr[4][2];
  bf16x8 afA[2][2], afB[2][2];   // phase-alternating A-fragment buffers

#define BPANEL(Bt_) do { \
      _Pragma("unroll") \
      for (int j = 0; j < 4; ++j) { \
        bfr[j][0] = *(const bf16x8*)((Bt_) + bBase + j * 16 * 64 + c0); \
        bfr[j][1] = *(const bf16x8*)((Bt_) + bBase + j * 16 * 64 + c1); \
      } \
    } while (0)

#define RD_AF(S_, q_) do { \
      _Pragma("unroll") \
      for (int i = 0; i < 2; ++i) { \
        S_[i][0] = *(const bf16x8*)(At + aBase + ((q_) * 32 + i * 16) * 64 + c0); \
        S_[i][1] = *(const bf16x8*)(At + aBase + ((q_) * 32 + i * 16) * 64 + c1); \
      } \
    } while (0)

#define MFMA16(q_, S_) do { \
      _Pragma("unroll") \
      for (int i = 0; i < 2; ++i) \
        _Pragma("unroll") \
        for (int j = 0; j < 4; ++j) { \
          acc[(q_) * 2 + i][j] = __builtin_amdgcn_mfma_f32_16x16x32_bf16( \
              S_[i][0], bfr[j][0], acc[(q_) * 2 + i][j], 0, 0, 0); \
          acc[(q_) * 2 + i][j] = __builtin_amdgcn_mfma_f32_16x16x32_bf16( \
              S_[i][1], bfr[j][1], acc[(q_) * 2 + i][j], 0, 0, 0); \
        } \
    } while (0)

  // Phase: {look-ahead ds_reads for next quadrant | GLDS issue} -> barrier ->
  // counted lgkm wait -> sched_barrier -> MFMA on current quadrant -> barrier.
#define PH(qcur_, SCUR_, SNXT_, qnxt_, ISSUE_STMT, LGKM_STR, END_STMT) do { \
      if ((qnxt_) >= 0) { RD_AF(SNXT_, ((qnxt_) & 3)); } \
      ISSUE_STMT; \
      asm volatile("" ::: "memory"); \
      __builtin_amdgcn_s_barrier(); \
      asm volatile(LGKM_STR ::: "memory"); \
      __builtin_amdgcn_sched_barrier(0); \
      __builtin_amdgcn_s_setprio(1); \
      MFMA16(qcur_, SCUR_); \
      __builtin_amdgcn_s_setprio(0); \
      END_STMT; \
      asm volatile("" ::: "memory"); \
      __builtin_amdgcn_s_barrier(); \
    } while (0)

#pragma unroll 1
  for (int t = 0; t < NT; ++t) {
    const bf16_t* At = lds + (t & 1) * 32768;
    const bf16_t* Bt = At + 16384;

    // Prime: B panel (8 reads) + quadrant-0 A-frags (4 reads).
    BPANEL(Bt);
    RD_AF(afA, 0);

    PH(0, afA, afB, 1, if (t + 1 < NT) ISSUE_A(0, t + 1),
       "s_waitcnt lgkmcnt(4)", (void)0);
    PH(1, afB, afA, 2, if (t + 1 < NT) ISSUE_A(1, t + 1),
       "s_waitcnt lgkmcnt(4)", (void)0);
    PH(2, afA, afB, 3, if (t + 2 < NT) ISSUE_B(0, t + 2),
       "s_waitcnt lgkmcnt(4)", (void)0);
    PH(3, afB, afA, -1, if (t + 2 < NT) ISSUE_B(1, t + 2),
       "s_waitcnt lgkmcnt(0)",
       if (t < NT - 2) { asm volatile("s_waitcnt vmcnt(4)" ::: "memory"); }
       else            { asm volatile("s_waitcnt vmcnt(0)" ::: "memory"); });
  }

  // Epilogue: C/D 16x16 layout: col = l16, row = quad*4 + reg.
#pragma unroll
  for (int ri = 0; ri < 8; ++ri) {
    const int mg = m0 + wm * 128 + ri * 16 + quad * 4;
#pragma unroll
    for (int j = 0; j < 4; ++j) {
      const int ng = n0 + wn * 64 + j * 16 + l16;
#pragma unroll
      for (int r = 0; r < 4; ++r)
        C[(size_t)(mg + r) * N + ng] = acc[ri][j][r];
    }
  }
}

// ---------------------------------------------------------------------------
extern "C" void kernel_launch(void* const* d_in, const int* in_sizes, int n_in,
                              void* d_out, int out_size, void* d_ws, size_t ws_size,
                              hipStream_t stream) {
  const float* x   = (const float*)d_in[0];
  const float* mod = (const float*)d_in[1];
  const float* W   = (const float*)d_in[2];
  float* out = (float*)d_out;

  const int D = 1024;
  const int Bn = in_sizes[0] / D;  // 8192
  const int Cn = in_sizes[2] / D;  // 4096

  bf16_t* a  = (bf16_t*)d_ws;                                             // B*D bf16
  bf16_t* Wb = (bf16_t*)((char*)d_ws + (size_t)Bn * D * sizeof(bf16_t));  // C*D bf16

  const int castBlocks = (Cn * D) / (256 * 8);   // 2048
  prep_kernel<<<Bn + castBlocks, 256, 0, stream>>>(x, mod, W, a, Wb, D, Bn);

  const int nwg = (Bn / 256) * (Cn / 256);  // 32*16 = 512, % 8 == 0
  gemm256_kernel<<<nwg, 512, 0, stream>>>(a, Wb, out, Bn, Cn);
}